// Round 2
// baseline (1220.985 us; speedup 1.0000x reference)
//
#include <hip/hip_runtime.h>
#include <stdint.h>
#include <stddef.h>

#define N_NODES 100000
#define N_EDGES 6400000
#define HIDDEN 16

__host__ __device__ inline uint32_t rotl32(uint32_t x, int n) {
    return (x << n) | (x >> (32 - n));
}

// Exact JAX threefry2x32 (20 rounds), matching jax/_src/prng.py
__host__ __device__ inline void threefry2x32(uint32_t k0, uint32_t k1,
                                             uint32_t x0, uint32_t x1,
                                             uint32_t& o0, uint32_t& o1) {
    uint32_t k2 = k0 ^ k1 ^ 0x1BD11BDAu;
    x0 += k0; x1 += k1;
    x0 += x1; x1 = rotl32(x1, 13); x1 ^= x0;
    x0 += x1; x1 = rotl32(x1, 15); x1 ^= x0;
    x0 += x1; x1 = rotl32(x1, 26); x1 ^= x0;
    x0 += x1; x1 = rotl32(x1,  6); x1 ^= x0;
    x0 += k1; x1 += k2 + 1u;
    x0 += x1; x1 = rotl32(x1, 17); x1 ^= x0;
    x0 += x1; x1 = rotl32(x1, 29); x1 ^= x0;
    x0 += x1; x1 = rotl32(x1, 16); x1 ^= x0;
    x0 += x1; x1 = rotl32(x1, 24); x1 ^= x0;
    x0 += k2; x1 += k0 + 2u;
    x0 += x1; x1 = rotl32(x1, 13); x1 ^= x0;
    x0 += x1; x1 = rotl32(x1, 15); x1 ^= x0;
    x0 += x1; x1 = rotl32(x1, 26); x1 ^= x0;
    x0 += x1; x1 = rotl32(x1,  6); x1 ^= x0;
    x0 += k0; x1 += k1 + 3u;
    x0 += x1; x1 = rotl32(x1, 17); x1 ^= x0;
    x0 += x1; x1 = rotl32(x1, 29); x1 ^= x0;
    x0 += x1; x1 = rotl32(x1, 16); x1 ^= x0;
    x0 += x1; x1 = rotl32(x1, 24); x1 ^= x0;
    x0 += k1; x1 += k2 + 4u;
    x0 += x1; x1 = rotl32(x1, 13); x1 ^= x0;
    x0 += x1; x1 = rotl32(x1, 15); x1 ^= x0;
    x0 += x1; x1 = rotl32(x1, 26); x1 ^= x0;
    x0 += x1; x1 = rotl32(x1,  6); x1 ^= x0;
    x0 += k2; x1 += k0 + 5u;
    o0 = x0; o1 = x1;
}

// jax_threefry_partitionable=True semantics (default in modern JAX):
// 32-bit random bits for flat index j (size < 2^32):
//   (a, b) = threefry2x32(key, hi=0, lo=j);  bits = a ^ b
__device__ inline float apply_dropout(float v, uint32_t flat, uint32_t k0, uint32_t k1) {
    uint32_t a, b;
    threefry2x32(k0, k1, 0u, flat, a, b);
    uint32_t bits = a ^ b;
    float u = __uint_as_float((bits >> 9) | 0x3F800000u) - 1.0f;
    return (u >= 0.3f) ? v * (1.0f / 0.7f) : 0.0f;
}

// ---- degree / dinv -------------------------------------------------------
__global__ void deg_init_kernel(float* deg) {
    int n = blockIdx.x * blockDim.x + threadIdx.x;
    if (n < N_NODES) deg[n] = 1.0f;  // self-loop
}

__global__ void deg_acc_kernel(const int* __restrict__ dst, float* deg) {
    int e = blockIdx.x * blockDim.x + threadIdx.x;
    if (e < N_EDGES) atomicAdd(&deg[dst[e]], 1.0f);
}

__global__ void dinv_kernel(float* deg) {
    int n = blockIdx.x * blockDim.x + threadIdx.x;
    if (n < N_NODES) deg[n] = 1.0f / sqrtf(deg[n]);
}

// ---- LayerNorm + W1 + pre-scale by dinv (one wave per node) --------------
__global__ void ln_w1_kernel(const float* __restrict__ x,
                             const float* __restrict__ gamma,
                             const float* __restrict__ beta,
                             const float* __restrict__ W1,
                             const float* __restrict__ dinv,
                             float* __restrict__ g1) {
    int wave = (blockIdx.x * blockDim.x + threadIdx.x) >> 6;
    int lane = threadIdx.x & 63;
    if (wave >= N_NODES) return;
    const float* xr = x + (size_t)wave * 128;
    float x0 = xr[lane], x1 = xr[lane + 64];

    float s = x0 + x1;
    #pragma unroll
    for (int o = 32; o; o >>= 1) s += __shfl_xor(s, o, 64);
    float mu = s * (1.0f / 128.0f);
    float d0 = x0 - mu, d1 = x1 - mu;
    float v = d0 * d0 + d1 * d1;
    #pragma unroll
    for (int o = 32; o; o >>= 1) v += __shfl_xor(v, o, 64);
    float rstd = rsqrtf(v * (1.0f / 128.0f) + 1e-5f);
    float xn0 = d0 * rstd * gamma[lane] + beta[lane];
    float xn1 = d1 * rstd * gamma[lane + 64] + beta[lane + 64];

    float p[HIDDEN];
    const float* wr0 = W1 + (size_t)lane * HIDDEN;
    const float* wr1 = W1 + (size_t)(lane + 64) * HIDDEN;
    #pragma unroll
    for (int j = 0; j < HIDDEN; j++) p[j] = xn0 * wr0[j] + xn1 * wr1[j];
    #pragma unroll
    for (int o = 32; o; o >>= 1) {
        #pragma unroll
        for (int j = 0; j < HIDDEN; j++) p[j] += __shfl_xor(p[j], o, 64);
    }
    if (lane < HIDDEN) g1[(size_t)wave * HIDDEN + lane] = p[lane] * dinv[wave];
}

// ---- edge scatter: acc[dst] += g[src]  (16 lanes per edge) ---------------
__global__ void scatter_kernel(const int* __restrict__ src,
                               const int* __restrict__ dst,
                               const float* __restrict__ g,
                               float* __restrict__ acc) {
    int e = blockIdx.x * 16 + (threadIdx.x >> 4);
    int f = threadIdx.x & 15;
    if (e >= N_EDGES) return;
    int s = src[e], d = dst[e];
    atomicAdd(&acc[(size_t)d * HIDDEN + f], g[(size_t)s * HIDDEN + f]);
}

// ---- finalize conv1: relu+dropout, then @W2, prescale by dinv ------------
// g2 may alias acc1 (each thread reads its own 16 before writing its own 16)
__global__ void finalize1_kernel(float* acc1_g2,            // in: acc1, out: g2
                                 const float* __restrict__ g1,
                                 const float* __restrict__ dinv,
                                 const float* __restrict__ b1,
                                 const float* __restrict__ W2,
                                 uint32_t k0, uint32_t k1) {
    __shared__ float sW2[HIDDEN * HIDDEN];
    int tb = threadIdx.x;
    if (tb < HIDDEN * HIDDEN) sW2[tb] = W2[tb];
    __syncthreads();
    int n = blockIdx.x * blockDim.x + tb;
    if (n >= N_NODES) return;
    float di = dinv[n];
    float h2[HIDDEN];
    #pragma unroll
    for (int j = 0; j < HIDDEN; j++) {
        int idx = n * HIDDEN + j;
        float v = di * (acc1_g2[idx] + g1[idx]) + b1[j];
        v = fmaxf(v, 0.0f);
        h2[j] = apply_dropout(v, (uint32_t)idx, k0, k1);
    }
    #pragma unroll
    for (int j = 0; j < HIDDEN; j++) {
        float a = 0.0f;
        #pragma unroll
        for (int i = 0; i < HIDDEN; i++) a += h2[i] * sW2[i * HIDDEN + j];
        acc1_g2[n * HIDDEN + j] = a * di;
    }
}

// ---- finalize conv2: relu + dropout -> out -------------------------------
__global__ void finalize2_kernel(const float* __restrict__ acc2,
                                 const float* __restrict__ g2,
                                 const float* __restrict__ dinv,
                                 const float* __restrict__ b2,
                                 float* __restrict__ out,
                                 uint32_t k0, uint32_t k1) {
    int j = blockIdx.x * blockDim.x + threadIdx.x;
    if (j >= N_NODES * HIDDEN) return;
    int n = j >> 4, f = j & 15;
    float v = dinv[n] * (acc2[j] + g2[j]) + b2[f];
    v = fmaxf(v, 0.0f);
    out[j] = apply_dropout(v, (uint32_t)j, k0, k1);
}

extern "C" void kernel_launch(void* const* d_in, const int* in_sizes, int n_in,
                              void* d_out, int out_size, void* d_ws, size_t ws_size,
                              hipStream_t stream) {
    const float* x     = (const float*)d_in[0];
    const int*   ei    = (const int*)d_in[1];
    const float* gamma = (const float*)d_in[2];
    const float* beta  = (const float*)d_in[3];
    const float* W1    = (const float*)d_in[4];
    const float* b1    = (const float*)d_in[5];
    const float* W2    = (const float*)d_in[6];
    const float* b2    = (const float*)d_in[7];
    float* out = (float*)d_out;
    const int* src = ei;
    const int* dst = ei + N_EDGES;

    // jax.random.split(jax.random.key(42)) under jax_threefry_partitionable:
    // child i = threefry2x32(key, hi=0, lo=i) -> (k0, k1)
    uint32_t dk1_0, dk1_1, dk2_0, dk2_1;
    threefry2x32(0u, 42u, 0u, 0u, dk1_0, dk1_1);
    threefry2x32(0u, 42u, 0u, 1u, dk2_0, dk2_1);

    // ws layout (floats): dinv [0,100000) | g1 | acc1
    // g2 aliases acc1; acc2 aliases g1 (g1 dead after finalize1).
    float* ws   = (float*)d_ws;
    float* dinv = ws;
    float* g1   = ws + N_NODES;
    float* acc1 = g1 + (size_t)N_NODES * HIDDEN;
    float* g2   = acc1;  // alias (finalize1 writes in place, per-thread safe)
    float* acc2 = g1;    // alias (zeroed after finalize1)

    const int NB_N   = (N_NODES + 255) / 256;          // 391
    const int NB_E   = (N_EDGES + 255) / 256;          // 25000
    const int NB_SC  = N_EDGES / 16;                   // 400000 (16 edges/block)
    const int NB_EL  = (N_NODES * HIDDEN) / 256;       // 6250

    hipMemsetAsync(acc1, 0, (size_t)N_NODES * HIDDEN * sizeof(float), stream);
    deg_init_kernel<<<NB_N, 256, 0, stream>>>(dinv);
    deg_acc_kernel<<<NB_E, 256, 0, stream>>>(dst, dinv);
    dinv_kernel<<<NB_N, 256, 0, stream>>>(dinv);
    ln_w1_kernel<<<(N_NODES + 3) / 4, 256, 0, stream>>>(x, gamma, beta, W1, dinv, g1);
    scatter_kernel<<<NB_SC, 256, 0, stream>>>(src, dst, g1, acc1);
    finalize1_kernel<<<NB_N, 256, 0, stream>>>(acc1, g1, dinv, b1, W2, dk1_0, dk1_1);
    hipMemsetAsync(acc2, 0, (size_t)N_NODES * HIDDEN * sizeof(float), stream);
    scatter_kernel<<<NB_SC, 256, 0, stream>>>(src, dst, g2, acc2);
    finalize2_kernel<<<NB_EL, 256, 0, stream>>>(acc2, g2, dinv, b2, out, dk2_0, dk2_1);
}